// Round 8
// baseline (595.008 us; speedup 1.0000x reference)
//
#include <hip/hip_runtime.h>

// PhaseEncoding: out[b,i,j,p] = 1.0f iff bins[p] <= (x[b,i,j] % 2pi) < bins[p+1]
// x fp32 in [0, 2pi), bins = fp32 linspace(0, 2pi, 9). Output [N][8] fp32.
//
// Layout (R1): thread owns ONE output float4 slot g (elem g>>1; lower 4
// bins if g even else upper 4). Consecutive lanes -> consecutive 16 B ->
// 1 KB contiguous per wave store; reads 128 B contiguous per wave.
//
// R8: (a) bin-edge select hoisted (g&1 == tid&1, loop-invariant: stride
// even); (b) two-phase unroll-8: issue 8 independent loads, then 8
// compute+store — 8 loads in flight per thread hides ~900cy HBM latency;
// (c) cached loads for x (2-way lane-pair reuse), nt stores (touch-once).

typedef float f32x4 __attribute__((ext_vector_type(4)));

__global__ __launch_bounds__(256) void PhaseEncoding_kernel(
    const float* __restrict__ x,
    const float* __restrict__ bins,
    f32x4* __restrict__ o4,
    int iters, int stride, int total4)
{
    // Uniform address -> scalar loads, broadcast free.
    float b0 = bins[0], b1 = bins[1], b2 = bins[2], b3 = bins[3], b4 = bins[4];
    float b5 = bins[5], b6 = bins[6], b7 = bins[7], b8 = bins[8];

    const float TWO_PI = 6.28318530717958647692f;

    int tid = blockIdx.x * blockDim.x + threadIdx.x;

    // Loop-invariant: which half of the 9 edges this lane compares against.
    bool hi = (tid & 1) != 0;
    float e0 = hi ? b4 : b0;
    float e1 = hi ? b5 : b1;
    float e2 = hi ? b6 : b2;
    float e3 = hi ? b7 : b3;
    float e4 = hi ? b8 : b4;

    int iters8 = iters & ~7;
    int it = 0;
    for (; it < iters8; it += 8) {
        float xv[8];
        #pragma unroll
        for (int u = 0; u < 8; ++u)
            xv[u] = x[(tid + (it + u) * stride) >> 1];

        #pragma unroll
        for (int u = 0; u < 8; ++u) {
            float xs = xv[u];
            float xn = (xs >= TWO_PI) ? (xs - TWO_PI) : xs;  // exact fmod, x in [0,4pi)
            f32x4 r;
            r.x = (xn >= e0 && xn < e1) ? 1.0f : 0.0f;
            r.y = (xn >= e1 && xn < e2) ? 1.0f : 0.0f;
            r.z = (xn >= e2 && xn < e3) ? 1.0f : 0.0f;
            r.w = (xn >= e3 && xn < e4) ? 1.0f : 0.0f;
            __builtin_nontemporal_store(r, &o4[tid + (it + u) * stride]);
        }
    }

    // Remainder iterations (none for the benched shape: iters = 64).
    for (; it < iters; ++it) {
        int g = tid + it * stride;
        float xs = x[g >> 1];
        float xn = (xs >= TWO_PI) ? (xs - TWO_PI) : xs;
        f32x4 r;
        r.x = (xn >= e0 && xn < e1) ? 1.0f : 0.0f;
        r.y = (xn >= e1 && xn < e2) ? 1.0f : 0.0f;
        r.z = (xn >= e2 && xn < e3) ? 1.0f : 0.0f;
        r.w = (xn >= e3 && xn < e4) ? 1.0f : 0.0f;
        __builtin_nontemporal_store(r, &o4[g]);
    }

    // Tail if total4 not a multiple of stride (empty for benched shape).
    int g = tid + iters * stride;
    if (g < total4) {
        float xs = x[g >> 1];
        float xn = (xs >= TWO_PI) ? (xs - TWO_PI) : xs;
        bool h2 = (g & 1) != 0;
        float f0 = h2 ? b4 : b0, f1 = h2 ? b5 : b1, f2 = h2 ? b6 : b2;
        float f3 = h2 ? b7 : b3, f4 = h2 ? b8 : b4;
        f32x4 r;
        r.x = (xn >= f0 && xn < f1) ? 1.0f : 0.0f;
        r.y = (xn >= f1 && xn < f2) ? 1.0f : 0.0f;
        r.z = (xn >= f2 && xn < f3) ? 1.0f : 0.0f;
        r.w = (xn >= f3 && xn < f4) ? 1.0f : 0.0f;
        o4[g] = r;
    }
}

extern "C" void kernel_launch(void* const* d_in, const int* in_sizes, int n_in,
                              void* d_out, int out_size, void* d_ws, size_t ws_size,
                              hipStream_t stream) {
    const float* x = (const float*)d_in[0];
    const float* bins = (const float*)d_in[1];
    f32x4* o4 = (f32x4*)d_out;

    int n = in_sizes[0];            // 8*4096*512 = 16,777,216
    int total4 = n * 2;             // output float4 slots

    int block = 256;
    int grid = 2048;                // 256 CU x 8 blocks resident
    int stride = grid * block;      // 524,288
    int iters = total4 / stride;    // 64 for the benched shape

    PhaseEncoding_kernel<<<grid, block, 0, stream>>>(x, bins, o4, iters, stride, total4);
}